// Round 14
// baseline (217.629 us; speedup 1.0000x reference)
//
#include <hip/hip_runtime.h>
#include <hip/hip_bf16.h>

// BPTT diagonal RNN: u = X @ B^T, h_t = lam*h_{t-1} + u_t (chunked scan).
// R14: fused GEMM, 128x256 tile, BK=32, 8 waves, 48KB LDS -> grid 512 with
// TRUE 2 blocks/CU (16 waves/CU) for cross-block hole filling. All-register
// staging (no gload_lds -> no vmcnt(0)-drain flaw, R13's diagnosed bug).
// R7-proven granule swizzle both operands. pass1 fused in epilogue (R12/R13-
// validated math); carry fused into pass3 (R13-validated). 2 launches total.

#define TDIM 8192
#define HDIM 2048
#define BM 128
#define BN 256
#define BK 32
#define NIT (HDIM / BK)        // 64 iters
#define LCH 64                 // scan chunk length
#define GCH (TDIM / LCH)       // 128 chunks

typedef float f32x4 __attribute__((ext_vector_type(4)));
typedef short s16x8 __attribute__((ext_vector_type(8)));

static __device__ __forceinline__ short f2bf(float f) {
  __bf16 b = (__bf16)f;                 // RNE f32->bf16
  return __builtin_bit_cast(short, b);
}

// ---------------- fused GEMM + pass1 epilogue -------------------------------
// LDS rows = 32 shorts (64B) = 4 x 16B granules; LDS[r][phys] holds logical
// granule phys ^ ((r>>1)&3)  [R7-measured 0-conflict on both rd and wr sides].
__global__ __launch_bounds__(512, 4) void gemm_hyb3(
    const float* __restrict__ X, const float* __restrict__ Bm,
    const float* __restrict__ lam,
    float* __restrict__ U, float* __restrict__ e) {
  __shared__ __align__(16) short As[2][BM * BK];   // 2 x 8 KiB
  __shared__ __align__(16) short Bs[2][BN * BK];   // 2 x 16 KiB

  // XCD swizzle: nwg=512 (%8==0, bijective)
  const int wg  = blockIdx.x;
  const int swz = (wg & 7) * 64 + (wg >> 3);
  const int tm = swz >> 3;              // 0..63 (row-tile)
  const int tn = swz & 7;               // 0..7  (col-tile)
  const int row0 = tm * BM, col0 = tn * BN;

  const int tid  = threadIdx.x;
  const int lane = tid & 63;
  const int wid  = tid >> 6;
  const int wr = (wid >> 2) * 64;       // 2 m-groups (chunk = wid>>2)
  const int wc = (wid & 3) * 64;        // 4 n-groups
  const int r16 = lane & 15;
  const int g4  = lane >> 4;            // k-granule 0..3

  // fragment read offsets: off = r*32 + ((g4 ^ ((r>>1)&3))*8)
  int offA[4], offB[4];
#pragma unroll
  for (int m = 0; m < 4; ++m) {
    const int r = wr + m * 16 + r16;
    offA[m] = r * 32 + ((g4 ^ ((r >> 1) & 3)) << 3);
  }
#pragma unroll
  for (int n = 0; n < 4; ++n) {
    const int r = wc + n * 16 + r16;
    offB[n] = r * 32 + ((g4 ^ ((r >> 1) & 3)) << 3);
  }

  // staging: thread t covers granule (row=t>>2, phys g=t&3); source logical
  // granule gl = (t&3) ^ ((t>>3)&3)  [= g ^ ((row>>1)&3), same for c-offsets
  // of +128 rows since 64 & 3 == 0]. Dest shorts = tid*8 (lane-linear b128).
  const int gl = (tid & 3) ^ ((tid >> 3) & 3);
  const float* gA = X  + (size_t)(row0 + (tid >> 2)) * HDIM + gl * 8;
  const float* gB = Bm + (size_t)(col0 + (tid >> 2)) * HDIM + gl * 8;

#define ISSUE_A(t_) do {                                                      \
    ra[0] = *(const f32x4*)(gA + (t_) * BK);                                  \
    ra[1] = *(const f32x4*)(gA + (t_) * BK + 4);                              \
  } while (0)

#define ISSUE_B(t_) do {                                                      \
    _Pragma("unroll") for (int c = 0; c < 2; ++c) {                           \
      const float* p = gB + (size_t)c * 128 * HDIM + (t_) * BK;               \
      rb[2 * c]     = *(const f32x4*)p;                                       \
      rb[2 * c + 1] = *(const f32x4*)(p + 4);                                 \
    }                                                                         \
  } while (0)

#define CVTWR_A(sl) do {                                                      \
    s16x8 v;                                                                  \
    v[0] = f2bf(ra[0][0]); v[1] = f2bf(ra[0][1]);                             \
    v[2] = f2bf(ra[0][2]); v[3] = f2bf(ra[0][3]);                             \
    v[4] = f2bf(ra[1][0]); v[5] = f2bf(ra[1][1]);                             \
    v[6] = f2bf(ra[1][2]); v[7] = f2bf(ra[1][3]);                             \
    *(s16x8*)&As[sl][tid * 8] = v;                                            \
  } while (0)

#define CVTWR_B(sl) do {                                                      \
    _Pragma("unroll") for (int c = 0; c < 2; ++c) {                           \
      s16x8 v;                                                                \
      v[0] = f2bf(rb[2*c][0]); v[1] = f2bf(rb[2*c][1]);                       \
      v[2] = f2bf(rb[2*c][2]); v[3] = f2bf(rb[2*c][3]);                       \
      v[4] = f2bf(rb[2*c+1][0]); v[5] = f2bf(rb[2*c+1][1]);                   \
      v[6] = f2bf(rb[2*c+1][2]); v[7] = f2bf(rb[2*c+1][3]);                   \
      *(s16x8*)&Bs[sl][(c * 512 + tid) * 8] = v;                              \
    }                                                                         \
  } while (0)

#define PHASE(sl) do {                                                        \
    s16x8 af[4], bfv[4];                                                      \
    _Pragma("unroll") for (int m = 0; m < 4; ++m)                             \
      af[m] = *(const s16x8*)&As[sl][offA[m]];                                \
    _Pragma("unroll") for (int n = 0; n < 4; ++n)                             \
      bfv[n] = *(const s16x8*)&Bs[sl][offB[n]];                               \
    __builtin_amdgcn_s_setprio(1);                                            \
    _Pragma("unroll") for (int m = 0; m < 4; ++m)                             \
      _Pragma("unroll") for (int n = 0; n < 4; ++n)                           \
        acc[m][n] = __builtin_amdgcn_mfma_f32_16x16x32_bf16(                  \
            af[m], bfv[n], acc[m][n], 0, 0, 0);                               \
    __builtin_amdgcn_s_setprio(0);                                            \
  } while (0)

  f32x4 acc[4][4] = {};
  f32x4 ra[2], rb[4];

  // prologue: tile 0 -> slot 0
  ISSUE_A(0);
  ISSUE_B(0);
  CVTWR_A(0);
  CVTWR_B(0);
  __syncthreads();

#pragma unroll 2
  for (int j = 0; j < NIT - 1; ++j) {
    const int cur = j & 1;
    ISSUE_A(j + 1);                     // 6 loads, issued early
    ISSUE_B(j + 1);
    PHASE(cur);                         // 8 ds_read + 16 MFMA (aging window)
    CVTWR_A(cur ^ 1);                   // consume-late
    CVTWR_B(cur ^ 1);
    __syncthreads();                    // nothing left in flight -> cheap
  }
  PHASE((NIT - 1) & 1);

  // ---------------- epilogue 1: write U (C/D map verified R1-R13) -----------
  const int crow = row0 + wr + (g4 << 2);
  const int ccol = col0 + wc + r16;
#pragma unroll
  for (int m = 0; m < 4; ++m)
#pragma unroll
    for (int n = 0; n < 4; ++n)
#pragma unroll
      for (int j = 0; j < 4; ++j)
        U[(size_t)(crow + m * 16 + j) * HDIM + ccol + n * 16] = acc[m][n][j];

  // ---------------- epilogue 2: fused pass1 (R12/R13-validated math) --------
  // Wave tile = 64 rows = one chunk.  e_j[c] = sum_{r} lam^(63-r) u_r
  //   = lam^{4(3-g4)} * Horner_m(lam^16, Horner_jj(lam, acc rows))
#pragma unroll
  for (int n = 0; n < 4; ++n) {
    const int c = ccol + n * 16;
    const float l  = lam[c];
    const float l2 = l * l;
    const float l4 = l2 * l2;
    const float l8 = l4 * l4;
    const float l16 = l8 * l8;
    float lg = 1.f;                     // lam^{4*(3-g4)}
    if (g4 < 3) lg = l4;
    if (g4 < 2) lg *= l4;
    if (g4 < 1) lg *= l4;
    float S = 0.f;
#pragma unroll
    for (int m = 0; m < 4; ++m) {
      const f32x4 a = acc[m][n];
      const float T = ((a[0] * l + a[1]) * l + a[2]) * l + a[3];
      S = S * l16 + T;
    }
    S *= lg;
    S += __shfl_xor(S, 16, 64);
    S += __shfl_xor(S, 32, 64);
    if (g4 == 0) {
      const int j = tm * 2 + (wid >> 2);   // global chunk index
      e[(size_t)j * HDIM + c] = S;
    }
  }

#undef ISSUE_A
#undef ISSUE_B
#undef CVTWR_A
#undef CVTWR_B
#undef PHASE
}

// ---------------- pass3 with inline carry (R13-validated) --------------------
__global__ void pass3f(float* __restrict__ U, const float* __restrict__ lam,
                       const float* __restrict__ e) {
  const int c = (blockIdx.y * 256 + threadIdx.x) * 4;
  const int j = blockIdx.x;
  const f32x4 l4 = *(const f32x4*)&lam[c];
  f32x4 p = l4;
#pragma unroll
  for (int i = 0; i < 6; ++i) p = p * p;   // lam^64
  f32x4 E = {0.f, 0.f, 0.f, 0.f};
  for (int jp = 0; jp < j; ++jp) {         // carry prefix (redundant, L2-hot)
    f32x4 ej = *(const f32x4*)&e[(size_t)jp * HDIM + c];
    E = p * E + ej;
  }
  float* up = U + (size_t)j * LCH * HDIM + c;
  f32x4 h = E;
#pragma unroll 4
  for (int t = 0; t < LCH; ++t) {
    f32x4 u4 = *(const f32x4*)up;
    h = l4 * h + u4;
    *(f32x4*)up = h;
    up += HDIM;
  }
}

// ---------------- fallback path (proven R1 pieces) --------------------------
__global__ __launch_bounds__(256, 2) void gemm_f32_fb(
    const float* __restrict__ X, const float* __restrict__ Bm,
    float* __restrict__ U) {
#define LDK 40
#define FBM 128
#define FBK 32
#define FNT (HDIM / FBK)
  __shared__ __align__(16) short As[2][FBM * LDK];
  __shared__ __align__(16) short Bs[2][FBM * LDK];
  const int wg  = blockIdx.x;
  const int cpx = (TDIM / FBM) * (HDIM / FBM) / 8;
  const int swz = (wg & 7) * cpx + (wg >> 3);
  const int tm = swz >> 4;
  const int tn = swz & 15;
  const int row0 = tm * FBM, col0 = tn * FBM;
  const int tid  = threadIdx.x;
  const int lane = tid & 63;
  const int wid  = tid >> 6;
  const int wr = (wid >> 1) * 64;
  const int wc = (wid & 1) * 64;
  const int srow = tid >> 2;
  const int sk   = (tid & 3) << 3;
  const float* gA  = X  + (size_t)(row0 + srow) * HDIM + sk;
  const float* gA2 = gA + 64 * HDIM;
  const float* gB  = Bm + (size_t)(col0 + srow) * HDIM + sk;
  const float* gB2 = gB + 64 * HDIM;
  f32x4 a00, a01, a10, a11, b00, b01, b10, b11;
#define LOADREG(kt) do {                                                      \
    const float* p;                                                           \
    p = gA  + (kt) * FBK; a00 = *(const f32x4*)p; a01 = *(const f32x4*)(p+4); \
    p = gA2 + (kt) * FBK; a10 = *(const f32x4*)p; a11 = *(const f32x4*)(p+4); \
    p = gB  + (kt) * FBK; b00 = *(const f32x4*)p; b01 = *(const f32x4*)(p+4); \
    p = gB2 + (kt) * FBK; b10 = *(const f32x4*)p; b11 = *(const f32x4*)(p+4); \
  } while (0)
#define CVT8(v, lo, hi) do {                                                  \
    v[0] = f2bf(lo[0]); v[1] = f2bf(lo[1]); v[2] = f2bf(lo[2]);               \
    v[3] = f2bf(lo[3]); v[4] = f2bf(hi[0]); v[5] = f2bf(hi[1]);               \
    v[6] = f2bf(hi[2]); v[7] = f2bf(hi[3]);                                   \
  } while (0)
#define DSWRITE(buf) do {                                                     \
    s16x8 v;                                                                  \
    CVT8(v, a00, a01); *(s16x8*)&As[buf][srow * LDK + sk] = v;                \
    CVT8(v, a10, a11); *(s16x8*)&As[buf][(srow + 64) * LDK + sk] = v;         \
    CVT8(v, b00, b01); *(s16x8*)&Bs[buf][srow * LDK + sk] = v;                \
    CVT8(v, b10, b11); *(s16x8*)&Bs[buf][(srow + 64) * LDK + sk] = v;         \
  } while (0)
  f32x4 acc[4][4] = {};
#define COMPUTE(buf) do {                                                     \
    const int r16_ = lane & 15;                                               \
    const int ks_  = (lane >> 4) * 8;                                         \
    s16x8 af[4], bfr[4];                                                      \
    _Pragma("unroll") for (int m = 0; m < 4; ++m)                             \
      af[m] = *(const s16x8*)&As[buf][(wr + m * 16 + r16_) * LDK + ks_];      \
    _Pragma("unroll") for (int n = 0; n < 4; ++n)                             \
      bfr[n] = *(const s16x8*)&Bs[buf][(wc + n * 16 + r16_) * LDK + ks_];     \
    _Pragma("unroll") for (int m = 0; m < 4; ++m)                             \
      _Pragma("unroll") for (int n = 0; n < 4; ++n)                           \
        acc[m][n] = __builtin_amdgcn_mfma_f32_16x16x32_bf16(                  \
            af[m], bfr[n], acc[m][n], 0, 0, 0);                               \
  } while (0)
  LOADREG(0);
  DSWRITE(0);
  __syncthreads();
#pragma unroll 2
  for (int kt = 0; kt < FNT; ++kt) {
    const int cur = kt & 1;
    if (kt + 1 < FNT) LOADREG(kt + 1);
    COMPUTE(cur);
    if (kt + 1 < FNT) DSWRITE(cur ^ 1);
    __syncthreads();
  }
  const int crow = wr + ((lane >> 4) << 2);
  const int ccol = wc + (lane & 15);
#pragma unroll
  for (int m = 0; m < 4; ++m)
#pragma unroll
    for (int n = 0; n < 4; ++n)
#pragma unroll
      for (int j = 0; j < 4; ++j)
        U[(size_t)(row0 + crow + m * 16 + j) * HDIM + (col0 + ccol + n * 16)] =
            acc[m][n][j];
#undef LOADREG
#undef CVT8
#undef DSWRITE
#undef COMPUTE
#undef LDK
#undef FBM
#undef FBK
#undef FNT
}

__global__ void scan_pass1(const float* __restrict__ U,
                           const float* __restrict__ lam,
                           float* __restrict__ e) {
  const int c = (blockIdx.y * 256 + threadIdx.x) * 4;
  const int j = blockIdx.x;
  const f32x4 l4 = *(const f32x4*)&lam[c];
  f32x4 h = {0.f, 0.f, 0.f, 0.f};
  const float* up = U + (size_t)j * LCH * HDIM + c;
#pragma unroll 4
  for (int t = 0; t < LCH; ++t) {
    f32x4 u4 = *(const f32x4*)up;
    h = l4 * h + u4;
    up += HDIM;
  }
  *(f32x4*)&e[(size_t)j * HDIM + c] = h;
}

extern "C" void kernel_launch(void* const* d_in, const int* in_sizes, int n_in,
                              void* d_out, int out_size, void* d_ws, size_t ws_size,
                              hipStream_t stream) {
  const float* X   = (const float*)d_in[0];
  const float* lam = (const float*)d_in[1];
  const float* Bm  = (const float*)d_in[2];
  float* U = (float*)d_out;              // u then h, in-place
  float* e = (float*)d_ws;               // 1 MB chunk-end values

  if (ws_size >= (size_t)GCH * HDIM * 4) {
    gemm_hyb3<<<dim3((TDIM / BM) * (HDIM / BN)), dim3(512), 0, stream>>>(
        X, Bm, lam, U, e);
    pass3f<<<dim3(GCH, HDIM / 1024), dim3(256), 0, stream>>>(U, lam, e);
  } else {
    gemm_f32_fb<<<dim3((TDIM / 128) * (HDIM / 128)), dim3(256), 0, stream>>>(
        X, Bm, U);
    scan_pass1<<<dim3(GCH, HDIM / 1024), dim3(256), 0, stream>>>(U, lam, e);
    pass3f<<<dim3(GCH, HDIM / 1024), dim3(256), 0, stream>>>(U, lam, e);
  }
}

// Round 15
// 119.156 us; speedup vs baseline: 1.8264x; 1.8264x over previous
//
#include <hip/hip_runtime.h>
#include <hip/hip_bf16.h>

// BPTT diagonal RNN: u = X @ B^T, h_t = lam*h_{t-1} + u_t (chunked scan).
// R15: champion composition. R12's gemm_fused2 (fused f32-in GEMM, BK=64 XOR
// swizzle 0-conflict, fused scan-pass1 epilogue) + R13-validated pass3f
// (on-the-fly carry prefix; scan_carry launch deleted). 2 launches total.

#define TDIM 8192
#define HDIM 2048
#define BM 256
#define BN 256
#define KT 64                  // K per iter (floats)
#define NIT (HDIM / KT)        // 32 iters
#define SLOT 16384             // shorts per LDS slot (256 rows x 64 k)
#define LCH 64                 // scan chunk length
#define GCH (TDIM / LCH)       // 128 chunks

typedef float f32x4 __attribute__((ext_vector_type(4)));
typedef short s16x4 __attribute__((ext_vector_type(4)));
typedef short s16x8 __attribute__((ext_vector_type(8)));

static __device__ __forceinline__ short f2bf(float f) {
  __bf16 b = (__bf16)f;                 // RNE f32->bf16
  return __builtin_bit_cast(short, b);
}

// ---------------- fused GEMM + pass1 epilogue (R12, unchanged) --------------
// 8 waves (2Mx4N), per-wave out 128x64 (8m x 4n frags of 16x16).
// LDS rows = 64 shorts (128B) = 8 x 16B chunks; phys chunk = logical ^ (row&7)
// -> conflict-free ds_read_b128 frags AND conflict-free ds_write staging. [R4]
__global__ __launch_bounds__(512, 2) void gemm_fused2(
    const float* __restrict__ X, const float* __restrict__ Bm,
    const float* __restrict__ lam,
    float* __restrict__ U, float* __restrict__ e) {
  extern __shared__ __align__(16) short smem[];
  short* As = smem;              // 2 slots x 16384 shorts (64 KiB)
  short* Bs = smem + 2 * SLOT;   // 2 slots x 16384 shorts (64 KiB)

  // XCD-aware swizzle: nwg=256 (%8==0, bijective)
  const int wg  = blockIdx.x;
  const int swz = (wg & 7) * 32 + (wg >> 3);
  const int tm = swz >> 3;              // 0..31
  const int tn = swz & 7;               // 0..7
  const int row0 = tm * BM, col0 = tn * BN;

  const int tid  = threadIdx.x;
  const int lane = tid & 63;
  const int wid  = tid >> 6;
  const int wr = (wid >> 2) * 128;      // 2 m-groups
  const int wc = (wid & 3) * 64;        // 4 n-groups

  // fragment ds_read offsets (kh=0); kh=1 = offset ^ 32 shorts  [R4-verified]
  const int g4 = lane >> 4;
  int offA[8], offB[4];
#pragma unroll
  for (int m = 0; m < 8; ++m) {
    const int r = wr + m * 16 + (lane & 15);
    offA[m] = r * 64 + ((g4 ^ (r & 3)) << 3) + (((r >> 2) & 1) << 5);
  }
#pragma unroll
  for (int n = 0; n < 4; ++n) {
    const int r = wc + n * 16 + (lane & 15);
    offB[n] = r * 64 + ((g4 ^ (r & 3)) << 3) + (((r >> 2) & 1) << 5);
  }

  // staging: load c in 0..7: row = (tid>>4) + c*32, floats [(tid&15)*4, +4)
  const int lrow   = tid >> 4;          // 0..31
  const int lcol16 = (tid & 15) * 4;    // float col within tile k-window
  const float* gA = X  + (size_t)(row0 + lrow) * HDIM + lcol16;
  const float* gB = Bm + (size_t)(col0 + lrow) * HDIM + lcol16;

  // ds_write (b64) offsets: wrow=lrow+c*32, chunk=(tid&15)>>1, half=tid&1
  int offW[8];
#pragma unroll
  for (int c = 0; c < 8; ++c) {
    const int wrow = lrow + c * 32;
    offW[c] = wrow * 64 + ((((tid & 15) >> 1) ^ (wrow & 7)) << 3) + (tid & 1) * 4;
  }

#define ISSUE(dst, gp, t_) do {                                               \
    _Pragma("unroll") for (int c = 0; c < 8; ++c)                             \
      dst[c] = *(const f32x4*)((gp) + (size_t)c * 32 * HDIM + (t_) * KT);     \
  } while (0)

#define CVTWR(arr, base, sl) do {                                             \
    _Pragma("unroll") for (int c = 0; c < 8; ++c) {                           \
      s16x4 v;                                                                \
      v[0] = f2bf(arr[c][0]); v[1] = f2bf(arr[c][1]);                         \
      v[2] = f2bf(arr[c][2]); v[3] = f2bf(arr[c][3]);                         \
      *(s16x4*)&base[(sl) * SLOT + offW[c]] = v;                              \
    }                                                                         \
  } while (0)

#define PHASE(sl, khx) do {                                                   \
    s16x8 af[8], bfv[4];                                                      \
    _Pragma("unroll") for (int m = 0; m < 8; ++m)                             \
      af[m] = *(const s16x8*)&As[(sl) * SLOT + (offA[m] ^ (khx))];            \
    _Pragma("unroll") for (int n = 0; n < 4; ++n)                             \
      bfv[n] = *(const s16x8*)&Bs[(sl) * SLOT + (offB[n] ^ (khx))];           \
    __builtin_amdgcn_s_setprio(1);                                            \
    _Pragma("unroll") for (int m = 0; m < 8; ++m)                             \
      _Pragma("unroll") for (int n = 0; n < 4; ++n)                           \
        acc[m][n] = __builtin_amdgcn_mfma_f32_16x16x32_bf16(                  \
            af[m], bfv[n], acc[m][n], 0, 0, 0);                               \
    __builtin_amdgcn_s_setprio(0);                                            \
  } while (0)

  f32x4 acc[8][4] = {};
  f32x4 ra[8], rb[8];

  // prologue: tile 0 -> slot 0 (R4 schedule)
  ISSUE(ra, gA, 0);
  ISSUE(rb, gB, 0);
  CVTWR(ra, As, 0);
  CVTWR(rb, Bs, 0);
  __syncthreads();

  for (int j = 0; j < NIT - 1; ++j) {
    const int cur = j & 1;
    ISSUE(ra, gA, j + 1);               // A loads for next tile (early issue)
    PHASE(cur, 0);                      // kh=0: 12 ds_read + 32 MFMA
    CVTWR(ra, As, cur ^ 1);             // A aged ~1 MFMA phase
    ISSUE(rb, gB, j + 1);               // B loads (covered by phase 1)
    PHASE(cur, 32);                     // kh=1
    CVTWR(rb, Bs, cur ^ 1);
    __syncthreads();
  }
  {
    const int cur = (NIT - 1) & 1;
    PHASE(cur, 0);
    PHASE(cur, 32);
  }

  // ---------------- epilogue 1: write U (C/D map verified R1-R14) -----------
  const int crow = row0 + wr + (g4 << 2);
  const int ccol = col0 + wc + (lane & 15);
#pragma unroll
  for (int m = 0; m < 8; ++m)
#pragma unroll
    for (int n = 0; n < 4; ++n)
#pragma unroll
      for (int j = 0; j < 4; ++j)
        U[(size_t)(crow + m * 16 + j) * HDIM + ccol + n * 16] = acc[m][n][j];

  // ---------------- epilogue 2: fused scan_pass1 (R12-validated) ------------
  // e_j[c] = lam^{4(3-g4)} * Horner_mq(lam^16, Horner_jj(lam, acc)) reduced
  // over the 4 g4-lane groups via shfl_xor(16,32).
#pragma unroll
  for (int n = 0; n < 4; ++n) {
    const int c = ccol + n * 16;
    const float l  = lam[c];
    const float l2 = l * l;
    const float l4 = l2 * l2;
    const float l8 = l4 * l4;
    const float l16 = l8 * l8;
    float lg = 1.f;                     // lam^{4*(3-g4)}
    if (g4 < 3) lg = l4;
    if (g4 < 2) lg *= l4;
    if (g4 < 1) lg *= l4;
#pragma unroll
    for (int half = 0; half < 2; ++half) {      // m 0..3 / 4..7
      float S = 0.f;
#pragma unroll
      for (int mq = 0; mq < 4; ++mq) {
        const f32x4 a = acc[half * 4 + mq][n];
        const float T = ((a[0] * l + a[1]) * l + a[2]) * l + a[3];
        S = S * l16 + T;
      }
      S *= lg;
      S += __shfl_xor(S, 16, 64);
      S += __shfl_xor(S, 32, 64);
      if (g4 == 0) {
        const int j = tm * 4 + (wr >> 6) + half;   // global chunk index
        e[(size_t)j * HDIM + c] = S;
      }
    }
  }

#undef ISSUE
#undef CVTWR
#undef PHASE
}

// ---------------- pass3 with inline carry (R13/R14-validated) ----------------
__global__ void pass3f(float* __restrict__ U, const float* __restrict__ lam,
                       const float* __restrict__ e) {
  const int c = (blockIdx.y * 256 + threadIdx.x) * 4;
  const int j = blockIdx.x;
  const f32x4 l4 = *(const f32x4*)&lam[c];
  f32x4 p = l4;
#pragma unroll
  for (int i = 0; i < 6; ++i) p = p * p;   // lam^64
  f32x4 E = {0.f, 0.f, 0.f, 0.f};
  for (int jp = 0; jp < j; ++jp) {         // carry prefix (redundant, L2-hot)
    f32x4 ej = *(const f32x4*)&e[(size_t)jp * HDIM + c];
    E = p * E + ej;
  }
  float* up = U + (size_t)j * LCH * HDIM + c;
  f32x4 h = E;
#pragma unroll 4
  for (int t = 0; t < LCH; ++t) {
    f32x4 u4 = *(const f32x4*)up;
    h = l4 * h + u4;
    *(f32x4*)up = h;
    up += HDIM;
  }
}

// ---------------- fallback path (proven R1 pieces) --------------------------
__global__ __launch_bounds__(256, 2) void gemm_f32_fb(
    const float* __restrict__ X, const float* __restrict__ Bm,
    float* __restrict__ U) {
#define LDK 40
#define FBM 128
#define FBK 32
#define FNT (HDIM / FBK)
  __shared__ __align__(16) short As[2][FBM * LDK];
  __shared__ __align__(16) short Bs[2][FBM * LDK];
  const int wg  = blockIdx.x;
  const int cpx = (TDIM / FBM) * (HDIM / FBM) / 8;
  const int swz = (wg & 7) * cpx + (wg >> 3);
  const int tm = swz >> 4;
  const int tn = swz & 15;
  const int row0 = tm * FBM, col0 = tn * FBM;
  const int tid  = threadIdx.x;
  const int lane = tid & 63;
  const int wid  = tid >> 6;
  const int wr = (wid >> 1) * 64;
  const int wc = (wid & 1) * 64;
  const int srow = tid >> 2;
  const int sk   = (tid & 3) << 3;
  const float* gA  = X  + (size_t)(row0 + srow) * HDIM + sk;
  const float* gA2 = gA + 64 * HDIM;
  const float* gB  = Bm + (size_t)(col0 + srow) * HDIM + sk;
  const float* gB2 = gB + 64 * HDIM;
  f32x4 a00, a01, a10, a11, b00, b01, b10, b11;
#define LOADREG(kt) do {                                                      \
    const float* p;                                                           \
    p = gA  + (kt) * FBK; a00 = *(const f32x4*)p; a01 = *(const f32x4*)(p+4); \
    p = gA2 + (kt) * FBK; a10 = *(const f32x4*)p; a11 = *(const f32x4*)(p+4); \
    p = gB  + (kt) * FBK; b00 = *(const f32x4*)p; b01 = *(const f32x4*)(p+4); \
    p = gB2 + (kt) * FBK; b10 = *(const f32x4*)p; b11 = *(const f32x4*)(p+4); \
  } while (0)
#define CVT8(v, lo, hi) do {                                                  \
    v[0] = f2bf(lo[0]); v[1] = f2bf(lo[1]); v[2] = f2bf(lo[2]);               \
    v[3] = f2bf(lo[3]); v[4] = f2bf(hi[0]); v[5] = f2bf(hi[1]);               \
    v[6] = f2bf(hi[2]); v[7] = f2bf(hi[3]);                                   \
  } while (0)
#define DSWRITE(buf) do {                                                     \
    s16x8 v;                                                                  \
    CVT8(v, a00, a01); *(s16x8*)&As[buf][srow * LDK + sk] = v;                \
    CVT8(v, a10, a11); *(s16x8*)&As[buf][(srow + 64) * LDK + sk] = v;         \
    CVT8(v, b00, b01); *(s16x8*)&Bs[buf][srow * LDK + sk] = v;                \
    CVT8(v, b10, b11); *(s16x8*)&Bs[buf][(srow + 64) * LDK + sk] = v;         \
  } while (0)
  f32x4 acc[4][4] = {};
#define COMPUTE(buf) do {                                                     \
    const int r16_ = lane & 15;                                               \
    const int ks_  = (lane >> 4) * 8;                                         \
    s16x8 af[4], bfr[4];                                                      \
    _Pragma("unroll") for (int m = 0; m < 4; ++m)                             \
      af[m] = *(const s16x8*)&As[buf][(wr + m * 16 + r16_) * LDK + ks_];      \
    _Pragma("unroll") for (int n = 0; n < 4; ++n)                             \
      bfr[n] = *(const s16x8*)&Bs[buf][(wc + n * 16 + r16_) * LDK + ks_];     \
    _Pragma("unroll") for (int m = 0; m < 4; ++m)                             \
      _Pragma("unroll") for (int n = 0; n < 4; ++n)                           \
        acc[m][n] = __builtin_amdgcn_mfma_f32_16x16x32_bf16(                  \
            af[m], bfr[n], acc[m][n], 0, 0, 0);                               \
  } while (0)
  LOADREG(0);
  DSWRITE(0);
  __syncthreads();
#pragma unroll 2
  for (int kt = 0; kt < FNT; ++kt) {
    const int cur = kt & 1;
    if (kt + 1 < FNT) LOADREG(kt + 1);
    COMPUTE(cur);
    if (kt + 1 < FNT) DSWRITE(cur ^ 1);
    __syncthreads();
  }
  const int crow = wr + ((lane >> 4) << 2);
  const int ccol = wc + (lane & 15);
#pragma unroll
  for (int m = 0; m < 4; ++m)
#pragma unroll
    for (int n = 0; n < 4; ++n)
#pragma unroll
      for (int j = 0; j < 4; ++j)
        U[(size_t)(row0 + crow + m * 16 + j) * HDIM + (col0 + ccol + n * 16)] =
            acc[m][n][j];
#undef LOADREG
#undef CVT8
#undef DSWRITE
#undef COMPUTE
#undef LDK
#undef FBM
#undef FBK
#undef FNT
}

__global__ void scan_pass1(const float* __restrict__ U,
                           const float* __restrict__ lam,
                           float* __restrict__ e) {
  const int c = (blockIdx.y * 256 + threadIdx.x) * 4;
  const int j = blockIdx.x;
  const f32x4 l4 = *(const f32x4*)&lam[c];
  f32x4 h = {0.f, 0.f, 0.f, 0.f};
  const float* up = U + (size_t)j * LCH * HDIM + c;
#pragma unroll 4
  for (int t = 0; t < LCH; ++t) {
    f32x4 u4 = *(const f32x4*)up;
    h = l4 * h + u4;
    up += HDIM;
  }
  *(f32x4*)&e[(size_t)j * HDIM + c] = h;
}

extern "C" void kernel_launch(void* const* d_in, const int* in_sizes, int n_in,
                              void* d_out, int out_size, void* d_ws, size_t ws_size,
                              hipStream_t stream) {
  const float* X   = (const float*)d_in[0];
  const float* lam = (const float*)d_in[1];
  const float* Bm  = (const float*)d_in[2];
  float* U = (float*)d_out;              // u then h, in-place
  float* e = (float*)d_ws;               // 1 MB chunk-end values

  if (ws_size >= (size_t)GCH * HDIM * 4) {
    hipFuncSetAttribute((const void*)gemm_fused2,
                        hipFuncAttributeMaxDynamicSharedMemorySize, 131072);
    gemm_fused2<<<dim3((TDIM / BM) * (HDIM / BN)), dim3(512), 131072, stream>>>(
        X, Bm, lam, U, e);
    pass3f<<<dim3(GCH, HDIM / 1024), dim3(256), 0, stream>>>(U, lam, e);
  } else {
    gemm_f32_fb<<<dim3((TDIM / 128) * (HDIM / 128)), dim3(256), 0, stream>>>(
        X, Bm, U);
    scan_pass1<<<dim3(GCH, HDIM / 1024), dim3(256), 0, stream>>>(U, lam, e);
    pass3f<<<dim3(GCH, HDIM / 1024), dim3(256), 0, stream>>>(U, lam, e);
  }
}

// Round 16
// 109.466 us; speedup vs baseline: 1.9881x; 1.0885x over previous
//
#include <hip/hip_runtime.h>
#include <hip/hip_bf16.h>

// BPTT diagonal RNN: u = X @ B^T, h_t = lam*h_{t-1} + u_t (chunked scan).
// R16 = R12 champion composition restored byte-for-byte (measured 109.6 us):
// gemm_fused2 (fused f32-in GEMM, BK=64 XOR swizzle 0-conflict, fused
// scan-pass1 epilogue) + scan_carry (parallel) + scan_pass3.
// R15's inline-carry pass3f removed: its serial dependent-load prefix chain
// cost ~10 us on late blocks (measured regression 119.2 vs 109.6).

#define TDIM 8192
#define HDIM 2048
#define BM 256
#define BN 256
#define KT 64                  // K per iter (floats)
#define NIT (HDIM / KT)        // 32 iters
#define SLOT 16384             // shorts per LDS slot (256 rows x 64 k)
#define LCH 64                 // scan chunk length
#define GCH (TDIM / LCH)       // 128 chunks

typedef float f32x4 __attribute__((ext_vector_type(4)));
typedef short s16x4 __attribute__((ext_vector_type(4)));
typedef short s16x8 __attribute__((ext_vector_type(8)));

static __device__ __forceinline__ short f2bf(float f) {
  __bf16 b = (__bf16)f;                 // RNE f32->bf16
  return __builtin_bit_cast(short, b);
}

// ---------------- fused GEMM + pass1 epilogue (R12, unchanged) --------------
// 8 waves (2Mx4N), per-wave out 128x64 (8m x 4n frags of 16x16).
// LDS rows = 64 shorts (128B) = 8 x 16B chunks; phys chunk = logical ^ (row&7)
// -> conflict-free ds_read_b128 frags AND conflict-free ds_write staging. [R4]
__global__ __launch_bounds__(512, 2) void gemm_fused2(
    const float* __restrict__ X, const float* __restrict__ Bm,
    const float* __restrict__ lam,
    float* __restrict__ U, float* __restrict__ e) {
  extern __shared__ __align__(16) short smem[];
  short* As = smem;              // 2 slots x 16384 shorts (64 KiB)
  short* Bs = smem + 2 * SLOT;   // 2 slots x 16384 shorts (64 KiB)

  // XCD-aware swizzle: nwg=256 (%8==0, bijective)
  const int wg  = blockIdx.x;
  const int swz = (wg & 7) * 32 + (wg >> 3);
  const int tm = swz >> 3;              // 0..31
  const int tn = swz & 7;               // 0..7
  const int row0 = tm * BM, col0 = tn * BN;

  const int tid  = threadIdx.x;
  const int lane = tid & 63;
  const int wid  = tid >> 6;
  const int wr = (wid >> 2) * 128;      // 2 m-groups
  const int wc = (wid & 3) * 64;        // 4 n-groups

  // fragment ds_read offsets (kh=0); kh=1 = offset ^ 32 shorts  [R4-verified]
  const int g4 = lane >> 4;
  int offA[8], offB[4];
#pragma unroll
  for (int m = 0; m < 8; ++m) {
    const int r = wr + m * 16 + (lane & 15);
    offA[m] = r * 64 + ((g4 ^ (r & 3)) << 3) + (((r >> 2) & 1) << 5);
  }
#pragma unroll
  for (int n = 0; n < 4; ++n) {
    const int r = wc + n * 16 + (lane & 15);
    offB[n] = r * 64 + ((g4 ^ (r & 3)) << 3) + (((r >> 2) & 1) << 5);
  }

  // staging: load c in 0..7: row = (tid>>4) + c*32, floats [(tid&15)*4, +4)
  const int lrow   = tid >> 4;          // 0..31
  const int lcol16 = (tid & 15) * 4;    // float col within tile k-window
  const float* gA = X  + (size_t)(row0 + lrow) * HDIM + lcol16;
  const float* gB = Bm + (size_t)(col0 + lrow) * HDIM + lcol16;

  // ds_write (b64) offsets: wrow=lrow+c*32, chunk=(tid&15)>>1, half=tid&1
  int offW[8];
#pragma unroll
  for (int c = 0; c < 8; ++c) {
    const int wrow = lrow + c * 32;
    offW[c] = wrow * 64 + ((((tid & 15) >> 1) ^ (wrow & 7)) << 3) + (tid & 1) * 4;
  }

#define ISSUE(dst, gp, t_) do {                                               \
    _Pragma("unroll") for (int c = 0; c < 8; ++c)                             \
      dst[c] = *(const f32x4*)((gp) + (size_t)c * 32 * HDIM + (t_) * KT);     \
  } while (0)

#define CVTWR(arr, base, sl) do {                                             \
    _Pragma("unroll") for (int c = 0; c < 8; ++c) {                           \
      s16x4 v;                                                                \
      v[0] = f2bf(arr[c][0]); v[1] = f2bf(arr[c][1]);                         \
      v[2] = f2bf(arr[c][2]); v[3] = f2bf(arr[c][3]);                         \
      *(s16x4*)&base[(sl) * SLOT + offW[c]] = v;                              \
    }                                                                         \
  } while (0)

#define PHASE(sl, khx) do {                                                   \
    s16x8 af[8], bfv[4];                                                      \
    _Pragma("unroll") for (int m = 0; m < 8; ++m)                             \
      af[m] = *(const s16x8*)&As[(sl) * SLOT + (offA[m] ^ (khx))];            \
    _Pragma("unroll") for (int n = 0; n < 4; ++n)                             \
      bfv[n] = *(const s16x8*)&Bs[(sl) * SLOT + (offB[n] ^ (khx))];           \
    __builtin_amdgcn_s_setprio(1);                                            \
    _Pragma("unroll") for (int m = 0; m < 8; ++m)                             \
      _Pragma("unroll") for (int n = 0; n < 4; ++n)                           \
        acc[m][n] = __builtin_amdgcn_mfma_f32_16x16x32_bf16(                  \
            af[m], bfv[n], acc[m][n], 0, 0, 0);                               \
    __builtin_amdgcn_s_setprio(0);                                            \
  } while (0)

  f32x4 acc[8][4] = {};
  f32x4 ra[8], rb[8];

  // prologue: tile 0 -> slot 0 (R4 schedule)
  ISSUE(ra, gA, 0);
  ISSUE(rb, gB, 0);
  CVTWR(ra, As, 0);
  CVTWR(rb, Bs, 0);
  __syncthreads();

  for (int j = 0; j < NIT - 1; ++j) {
    const int cur = j & 1;
    ISSUE(ra, gA, j + 1);               // A loads for next tile (early issue)
    PHASE(cur, 0);                      // kh=0: 12 ds_read + 32 MFMA
    CVTWR(ra, As, cur ^ 1);             // A aged ~1 MFMA phase
    ISSUE(rb, gB, j + 1);               // B loads (covered by phase 1)
    PHASE(cur, 32);                     // kh=1
    CVTWR(rb, Bs, cur ^ 1);
    __syncthreads();
  }
  {
    const int cur = (NIT - 1) & 1;
    PHASE(cur, 0);
    PHASE(cur, 32);
  }

  // ---------------- epilogue 1: write U (C/D map verified R1-R15) -----------
  const int crow = row0 + wr + (g4 << 2);
  const int ccol = col0 + wc + (lane & 15);
#pragma unroll
  for (int m = 0; m < 8; ++m)
#pragma unroll
    for (int n = 0; n < 4; ++n)
#pragma unroll
      for (int j = 0; j < 4; ++j)
        U[(size_t)(crow + m * 16 + j) * HDIM + ccol + n * 16] = acc[m][n][j];

  // ---------------- epilogue 2: fused scan_pass1 (R12-validated) ------------
  // e_j[c] = lam^{4(3-g4)} * Horner_mq(lam^16, Horner_jj(lam, acc)) reduced
  // over the 4 g4-lane groups via shfl_xor(16,32).
#pragma unroll
  for (int n = 0; n < 4; ++n) {
    const int c = ccol + n * 16;
    const float l  = lam[c];
    const float l2 = l * l;
    const float l4 = l2 * l2;
    const float l8 = l4 * l4;
    const float l16 = l8 * l8;
    float lg = 1.f;                     // lam^{4*(3-g4)}
    if (g4 < 3) lg = l4;
    if (g4 < 2) lg *= l4;
    if (g4 < 1) lg *= l4;
#pragma unroll
    for (int half = 0; half < 2; ++half) {      // m 0..3 / 4..7
      float S = 0.f;
#pragma unroll
      for (int mq = 0; mq < 4; ++mq) {
        const f32x4 a = acc[half * 4 + mq][n];
        const float T = ((a[0] * l + a[1]) * l + a[2]) * l + a[3];
        S = S * l16 + T;
      }
      S *= lg;
      S += __shfl_xor(S, 16, 64);
      S += __shfl_xor(S, 32, 64);
      if (g4 == 0) {
        const int j = tm * 4 + (wr >> 6) + half;   // global chunk index
        e[(size_t)j * HDIM + c] = S;
      }
    }
  }

#undef ISSUE
#undef CVTWR
#undef PHASE
}

// ---------------- scan pass 2: carry scan over chunks (in-place on e) --------
__global__ void scan_carry(float* __restrict__ e, const float* __restrict__ lam) {
  const int c = (blockIdx.x * 256 + threadIdx.x) * 4;
  const f32x4 l4 = *(const f32x4*)&lam[c];
  f32x4 p = l4;
#pragma unroll
  for (int i = 0; i < 6; ++i) p = p * p;   // lam^64
  f32x4 E = {0.f, 0.f, 0.f, 0.f};
  for (int j = 0; j < GCH; ++j) {
    f32x4 ej = *(const f32x4*)&e[(size_t)j * HDIM + c];
    *(f32x4*)&e[(size_t)j * HDIM + c] = E;  // carry into chunk j = E_{j-1}
    E = p * E + ej;
  }
}

// ---------------- scan pass 3: final scan with carry, in-place U -> h --------
__global__ void scan_pass3(float* __restrict__ U, const float* __restrict__ lam,
                           const float* __restrict__ carry) {
  const int c = (blockIdx.y * 256 + threadIdx.x) * 4;
  const int j = blockIdx.x;
  const f32x4 l4 = *(const f32x4*)&lam[c];
  f32x4 h = *(const f32x4*)&carry[(size_t)j * HDIM + c];
  float* up = U + (size_t)j * LCH * HDIM + c;
#pragma unroll 4
  for (int t = 0; t < LCH; ++t) {
    f32x4 u4 = *(const f32x4*)up;
    h = l4 * h + u4;
    *(f32x4*)up = h;
    up += HDIM;
  }
}

// ---------------- fallback path (proven R1 pieces) --------------------------
__global__ __launch_bounds__(256, 2) void gemm_f32_fb(
    const float* __restrict__ X, const float* __restrict__ Bm,
    float* __restrict__ U) {
#define LDK 40
#define FBM 128
#define FBK 32
#define FNT (HDIM / FBK)
  __shared__ __align__(16) short As[2][FBM * LDK];
  __shared__ __align__(16) short Bs[2][FBM * LDK];
  const int wg  = blockIdx.x;
  const int cpx = (TDIM / FBM) * (HDIM / FBM) / 8;
  const int swz = (wg & 7) * cpx + (wg >> 3);
  const int tm = swz >> 4;
  const int tn = swz & 15;
  const int row0 = tm * FBM, col0 = tn * FBM;
  const int tid  = threadIdx.x;
  const int lane = tid & 63;
  const int wid  = tid >> 6;
  const int wr = (wid >> 1) * 64;
  const int wc = (wid & 1) * 64;
  const int srow = tid >> 2;
  const int sk   = (tid & 3) << 3;
  const float* gA  = X  + (size_t)(row0 + srow) * HDIM + sk;
  const float* gA2 = gA + 64 * HDIM;
  const float* gB  = Bm + (size_t)(col0 + srow) * HDIM + sk;
  const float* gB2 = gB + 64 * HDIM;
  f32x4 a00, a01, a10, a11, b00, b01, b10, b11;
#define LOADREG(kt) do {                                                      \
    const float* p;                                                           \
    p = gA  + (kt) * FBK; a00 = *(const f32x4*)p; a01 = *(const f32x4*)(p+4); \
    p = gA2 + (kt) * FBK; a10 = *(const f32x4*)p; a11 = *(const f32x4*)(p+4); \
    p = gB  + (kt) * FBK; b00 = *(const f32x4*)p; b01 = *(const f32x4*)(p+4); \
    p = gB2 + (kt) * FBK; b10 = *(const f32x4*)p; b11 = *(const f32x4*)(p+4); \
  } while (0)
#define CVT8(v, lo, hi) do {                                                  \
    v[0] = f2bf(lo[0]); v[1] = f2bf(lo[1]); v[2] = f2bf(lo[2]);               \
    v[3] = f2bf(lo[3]); v[4] = f2bf(hi[0]); v[5] = f2bf(hi[1]);               \
    v[6] = f2bf(hi[2]); v[7] = f2bf(hi[3]);                                   \
  } while (0)
#define DSWRITE(buf) do {                                                     \
    s16x8 v;                                                                  \
    CVT8(v, a00, a01); *(s16x8*)&As[buf][srow * LDK + sk] = v;                \
    CVT8(v, a10, a11); *(s16x8*)&As[buf][(srow + 64) * LDK + sk] = v;         \
    CVT8(v, b00, b01); *(s16x8*)&Bs[buf][srow * LDK + sk] = v;                \
    CVT8(v, b10, b11); *(s16x8*)&Bs[buf][(srow + 64) * LDK + sk] = v;         \
  } while (0)
  f32x4 acc[4][4] = {};
#define COMPUTE(buf) do {                                                     \
    const int r16_ = lane & 15;                                               \
    const int ks_  = (lane >> 4) * 8;                                         \
    s16x8 af[4], bfr[4];                                                      \
    _Pragma("unroll") for (int m = 0; m < 4; ++m)                             \
      af[m] = *(const s16x8*)&As[buf][(wr + m * 16 + r16_) * LDK + ks_];      \
    _Pragma("unroll") for (int n = 0; n < 4; ++n)                             \
      bfr[n] = *(const s16x8*)&Bs[buf][(wc + n * 16 + r16_) * LDK + ks_];     \
    _Pragma("unroll") for (int m = 0; m < 4; ++m)                             \
      _Pragma("unroll") for (int n = 0; n < 4; ++n)                           \
        acc[m][n] = __builtin_amdgcn_mfma_f32_16x16x32_bf16(                  \
            af[m], bfr[n], acc[m][n], 0, 0, 0);                               \
  } while (0)
  LOADREG(0);
  DSWRITE(0);
  __syncthreads();
#pragma unroll 2
  for (int kt = 0; kt < FNT; ++kt) {
    const int cur = kt & 1;
    if (kt + 1 < FNT) LOADREG(kt + 1);
    COMPUTE(cur);
    if (kt + 1 < FNT) DSWRITE(cur ^ 1);
    __syncthreads();
  }
  const int crow = wr + ((lane >> 4) << 2);
  const int ccol = wc + (lane & 15);
#pragma unroll
  for (int m = 0; m < 4; ++m)
#pragma unroll
    for (int n = 0; n < 4; ++n)
#pragma unroll
      for (int j = 0; j < 4; ++j)
        U[(size_t)(row0 + crow + m * 16 + j) * HDIM + (col0 + ccol + n * 16)] =
            acc[m][n][j];
#undef LOADREG
#undef CVT8
#undef DSWRITE
#undef COMPUTE
#undef LDK
#undef FBM
#undef FBK
#undef FNT
}

__global__ void scan_pass1(const float* __restrict__ U,
                           const float* __restrict__ lam,
                           float* __restrict__ e) {
  const int c = (blockIdx.y * 256 + threadIdx.x) * 4;
  const int j = blockIdx.x;
  const f32x4 l4 = *(const f32x4*)&lam[c];
  f32x4 h = {0.f, 0.f, 0.f, 0.f};
  const float* up = U + (size_t)j * LCH * HDIM + c;
#pragma unroll 4
  for (int t = 0; t < LCH; ++t) {
    f32x4 u4 = *(const f32x4*)up;
    h = l4 * h + u4;
    up += HDIM;
  }
  *(f32x4*)&e[(size_t)j * HDIM + c] = h;
}

extern "C" void kernel_launch(void* const* d_in, const int* in_sizes, int n_in,
                              void* d_out, int out_size, void* d_ws, size_t ws_size,
                              hipStream_t stream) {
  const float* X   = (const float*)d_in[0];
  const float* lam = (const float*)d_in[1];
  const float* Bm  = (const float*)d_in[2];
  float* U = (float*)d_out;              // u then h, in-place
  float* e = (float*)d_ws;               // 1 MB chunk-end values

  if (ws_size >= (size_t)GCH * HDIM * 4) {
    hipFuncSetAttribute((const void*)gemm_fused2,
                        hipFuncAttributeMaxDynamicSharedMemorySize, 131072);
    gemm_fused2<<<dim3((TDIM / BM) * (HDIM / BN)), dim3(512), 131072, stream>>>(
        X, Bm, lam, U, e);
    scan_carry<<<dim3(HDIM / 1024), dim3(256), 0, stream>>>(e, lam);
    scan_pass3<<<dim3(GCH, HDIM / 1024), dim3(256), 0, stream>>>(U, lam, e);
  } else {
    gemm_f32_fb<<<dim3((TDIM / 128) * (HDIM / 128)), dim3(256), 0, stream>>>(
        X, Bm, U);
    scan_pass1<<<dim3(GCH, HDIM / 1024), dim3(256), 0, stream>>>(U, lam, e);
    scan_carry<<<dim3(HDIM / 1024), dim3(256), 0, stream>>>(e, lam);
    scan_pass3<<<dim3(GCH, HDIM / 1024), dim3(256), 0, stream>>>(U, lam, e);
  }
}

// Round 17
// 109.465 us; speedup vs baseline: 1.9881x; 1.0000x over previous
//
#include <hip/hip_runtime.h>
#include <hip/hip_bf16.h>

// BPTT diagonal RNN: u = X @ B^T, h_t = lam*h_{t-1} + u_t (chunked scan).
// R17: champion (R12/R16) with B staged from a pre-converted bf16 copy via
// REGISTER loads (not gload_lds -> no barrier-drain trap). Removes B's
// per-iter cvt work (32 cvt + 4 extra loads + 4 writes per thread-iter).
// A path, LDS layout (phys chunk = logical ^ (row&7), 0-conflict), fused
// pass1 epilogue, scan_carry, scan_pass3 unchanged from the champion.

#define TDIM 8192
#define HDIM 2048
#define BM 256
#define BN 256
#define KT 64                  // K per iter (floats / shorts)
#define NIT (HDIM / KT)        // 32 iters
#define SLOT 16384             // shorts per LDS slot (256 rows x 64 k)
#define LCH 64                 // scan chunk length
#define GCH (TDIM / LCH)       // 128 chunks

#define BBF_BYTES (HDIM * HDIM * 2)   // 8 MB
#define E_BYTES   (GCH * HDIM * 4)    // 1 MB
#define WS_NEED   ((size_t)BBF_BYTES + E_BYTES)

typedef float f32x4 __attribute__((ext_vector_type(4)));
typedef short s16x4 __attribute__((ext_vector_type(4)));
typedef short s16x8 __attribute__((ext_vector_type(8)));

static __device__ __forceinline__ short f2bf(float f) {
  __bf16 b = (__bf16)f;                 // RNE f32->bf16
  return __builtin_bit_cast(short, b);
}

// ---------------- B: f32 -> bf16 (24 MB traffic; R13-measured ~6 us) --------
__global__ void cvt_B(const float* __restrict__ src, short* __restrict__ dst) {
  const int base = blockIdx.x * 1024;   // f32x4 items, 1024 blocks
  const int t = threadIdx.x;
  f32x4 v0 = *(const f32x4*)(src + (size_t)(base +   0 + t) * 4);
  f32x4 v1 = *(const f32x4*)(src + (size_t)(base + 256 + t) * 4);
  f32x4 v2 = *(const f32x4*)(src + (size_t)(base + 512 + t) * 4);
  f32x4 v3 = *(const f32x4*)(src + (size_t)(base + 768 + t) * 4);
#define STORE1(v_, off_) do {                                                 \
    s16x4 o;                                                                  \
    o[0] = f2bf(v_[0]); o[1] = f2bf(v_[1]);                                   \
    o[2] = f2bf(v_[2]); o[3] = f2bf(v_[3]);                                   \
    *(s16x4*)(dst + (size_t)(base + (off_) + t) * 4) = o;                     \
  } while (0)
  STORE1(v0, 0); STORE1(v1, 256); STORE1(v2, 512); STORE1(v3, 768);
#undef STORE1
}

// ---------------- fused GEMM + pass1 epilogue (B from bf16) -----------------
// 8 waves (2Mx4N), per-wave out 128x64 (8m x 4n frags of 16x16).
// LDS rows = 64 shorts (128B) = 8 x 16B chunks; phys chunk = logical ^ (row&7)
// -> conflict-free ds_read_b128 frags AND conflict-free ds_write staging.
__global__ __launch_bounds__(512, 2) void gemm_fused3(
    const float* __restrict__ X, const short* __restrict__ Bb,
    const float* __restrict__ lam,
    float* __restrict__ U, float* __restrict__ e) {
  extern __shared__ __align__(16) short smem[];
  short* As = smem;              // 2 slots x 16384 shorts (64 KiB)
  short* Bs = smem + 2 * SLOT;   // 2 slots x 16384 shorts (64 KiB)

  // XCD-aware swizzle: nwg=256 (%8==0, bijective)
  const int wg  = blockIdx.x;
  const int swz = (wg & 7) * 32 + (wg >> 3);
  const int tm = swz >> 3;              // 0..31
  const int tn = swz & 7;               // 0..7
  const int row0 = tm * BM, col0 = tn * BN;

  const int tid  = threadIdx.x;
  const int lane = tid & 63;
  const int wid  = tid >> 6;
  const int wr = (wid >> 2) * 128;      // 2 m-groups
  const int wc = (wid & 3) * 64;        // 4 n-groups

  // fragment ds_read offsets (kh=0); kh=1 = offset ^ 32 shorts  [R4-verified]
  const int g4 = lane >> 4;
  int offA[8], offB[4];
#pragma unroll
  for (int m = 0; m < 8; ++m) {
    const int r = wr + m * 16 + (lane & 15);
    offA[m] = r * 64 + ((g4 ^ (r & 3)) << 3) + (((r >> 2) & 1) << 5);
  }
#pragma unroll
  for (int n = 0; n < 4; ++n) {
    const int r = wc + n * 16 + (lane & 15);
    offB[n] = r * 64 + ((g4 ^ (r & 3)) << 3) + (((r >> 2) & 1) << 5);
  }

  // A staging (unchanged): load c in 0..7: row=(tid>>4)+c*32,
  // floats [(tid&15)*4, +4)
  const int lrow   = tid >> 4;          // 0..31
  const int lcol16 = (tid & 15) * 4;
  const float* gA = X + (size_t)(row0 + lrow) * HDIM + lcol16;

  // A ds_write (b64) offsets: wrow=lrow+c*32, chunk=(tid&15)>>1, half=tid&1
  int offW[8];
#pragma unroll
  for (int c = 0; c < 8; ++c) {
    const int wrow = lrow + c * 32;
    offW[c] = wrow * 64 + ((((tid & 15) >> 1) ^ (wrow & 7)) << 3) + (tid & 1) * 4;
  }

  // B staging from bf16: unit u = c*512 + tid -> LDS shorts [u*8, u*8+8)
  // = (row=u>>3, phys chunk=u&7). Source logical chunk l = phys ^ (row&7)
  // = (tid&7) ^ ((tid>>3)&7)  [c*64 = 0 mod 8 drops out].
  const int lB = (tid & 7) ^ ((tid >> 3) & 7);
  const short* gBb = Bb + (size_t)(col0 + (tid >> 3)) * HDIM + lB * 8;

#define ISSUE_A(t_) do {                                                      \
    _Pragma("unroll") for (int c = 0; c < 8; ++c)                             \
      ra[c] = *(const f32x4*)(gA + (size_t)c * 32 * HDIM + (t_) * KT);        \
  } while (0)

#define CVTWR_A(sl) do {                                                      \
    _Pragma("unroll") for (int c = 0; c < 8; ++c) {                           \
      s16x4 v;                                                                \
      v[0] = f2bf(ra[c][0]); v[1] = f2bf(ra[c][1]);                           \
      v[2] = f2bf(ra[c][2]); v[3] = f2bf(ra[c][3]);                           \
      *(s16x4*)&As[(sl) * SLOT + offW[c]] = v;                                \
    }                                                                         \
  } while (0)

#define ISSUE_B(t_) do {                                                      \
    _Pragma("unroll") for (int c = 0; c < 4; ++c)                             \
      rb[c] = *(const s16x8*)(gBb + (size_t)c * 64 * HDIM + (t_) * KT);       \
  } while (0)

#define WR_B(sl) do {                                                         \
    _Pragma("unroll") for (int c = 0; c < 4; ++c)                             \
      *(s16x8*)&Bs[(sl) * SLOT + (c * 512 + tid) * 8] = rb[c];                \
  } while (0)

#define PHASE(sl, khx) do {                                                   \
    s16x8 af[8], bfv[4];                                                      \
    _Pragma("unroll") for (int m = 0; m < 8; ++m)                             \
      af[m] = *(const s16x8*)&As[(sl) * SLOT + (offA[m] ^ (khx))];            \
    _Pragma("unroll") for (int n = 0; n < 4; ++n)                             \
      bfv[n] = *(const s16x8*)&Bs[(sl) * SLOT + (offB[n] ^ (khx))];           \
    __builtin_amdgcn_s_setprio(1);                                            \
    _Pragma("unroll") for (int m = 0; m < 8; ++m)                             \
      _Pragma("unroll") for (int n = 0; n < 4; ++n)                           \
        acc[m][n] = __builtin_amdgcn_mfma_f32_16x16x32_bf16(                  \
            af[m], bfv[n], acc[m][n], 0, 0, 0);                               \
    __builtin_amdgcn_s_setprio(0);                                            \
  } while (0)

  f32x4 acc[8][4] = {};
  f32x4 ra[8];
  s16x8 rb[4];

  // prologue: tile 0 -> slot 0 (R4 schedule shape)
  ISSUE_A(0);
  ISSUE_B(0);
  CVTWR_A(0);
  WR_B(0);
  __syncthreads();

  for (int j = 0; j < NIT - 1; ++j) {
    const int cur = j & 1;
    ISSUE_A(j + 1);                     // A loads for next tile (early issue)
    PHASE(cur, 0);                      // kh=0: 12 ds_read + 32 MFMA
    CVTWR_A(cur ^ 1);                   // A aged ~1 MFMA phase
    ISSUE_B(j + 1);                     // 4 bf16x8 loads (L3-resident Bb)
    PHASE(cur, 32);                     // kh=1
    WR_B(cur ^ 1);                      // B aged ~1 MFMA phase
    __syncthreads();
  }
  {
    const int cur = (NIT - 1) & 1;
    PHASE(cur, 0);
    PHASE(cur, 32);
  }

  // ---------------- epilogue 1: write U (C/D map verified R1-R16) -----------
  const int crow = row0 + wr + (g4 << 2);
  const int ccol = col0 + wc + (lane & 15);
#pragma unroll
  for (int m = 0; m < 8; ++m)
#pragma unroll
    for (int n = 0; n < 4; ++n)
#pragma unroll
      for (int j = 0; j < 4; ++j)
        U[(size_t)(crow + m * 16 + j) * HDIM + ccol + n * 16] = acc[m][n][j];

  // ---------------- epilogue 2: fused scan_pass1 (R12-validated) ------------
#pragma unroll
  for (int n = 0; n < 4; ++n) {
    const int c = ccol + n * 16;
    const float l  = lam[c];
    const float l2 = l * l;
    const float l4 = l2 * l2;
    const float l8 = l4 * l4;
    const float l16 = l8 * l8;
    float lg = 1.f;                     // lam^{4*(3-g4)}
    if (g4 < 3) lg = l4;
    if (g4 < 2) lg *= l4;
    if (g4 < 1) lg *= l4;
#pragma unroll
    for (int half = 0; half < 2; ++half) {      // m 0..3 / 4..7
      float S = 0.f;
#pragma unroll
      for (int mq = 0; mq < 4; ++mq) {
        const f32x4 a = acc[half * 4 + mq][n];
        const float T = ((a[0] * l + a[1]) * l + a[2]) * l + a[3];
        S = S * l16 + T;
      }
      S *= lg;
      S += __shfl_xor(S, 16, 64);
      S += __shfl_xor(S, 32, 64);
      if (g4 == 0) {
        const int j = tm * 4 + (wr >> 6) + half;   // global chunk index
        e[(size_t)j * HDIM + c] = S;
      }
    }
  }

#undef ISSUE_A
#undef CVTWR_A
#undef ISSUE_B
#undef WR_B
#undef PHASE
}

// ---------------- scan pass 2: carry scan over chunks (in-place on e) --------
__global__ void scan_carry(float* __restrict__ e, const float* __restrict__ lam) {
  const int c = (blockIdx.x * 256 + threadIdx.x) * 4;
  const f32x4 l4 = *(const f32x4*)&lam[c];
  f32x4 p = l4;
#pragma unroll
  for (int i = 0; i < 6; ++i) p = p * p;   // lam^64
  f32x4 E = {0.f, 0.f, 0.f, 0.f};
  for (int j = 0; j < GCH; ++j) {
    f32x4 ej = *(const f32x4*)&e[(size_t)j * HDIM + c];
    *(f32x4*)&e[(size_t)j * HDIM + c] = E;  // carry into chunk j = E_{j-1}
    E = p * E + ej;
  }
}

// ---------------- scan pass 3: final scan with carry, in-place U -> h --------
__global__ void scan_pass3(float* __restrict__ U, const float* __restrict__ lam,
                           const float* __restrict__ carry) {
  const int c = (blockIdx.y * 256 + threadIdx.x) * 4;
  const int j = blockIdx.x;
  const f32x4 l4 = *(const f32x4*)&lam[c];
  f32x4 h = *(const f32x4*)&carry[(size_t)j * HDIM + c];
  float* up = U + (size_t)j * LCH * HDIM + c;
#pragma unroll 4
  for (int t = 0; t < LCH; ++t) {
    f32x4 u4 = *(const f32x4*)up;
    h = l4 * h + u4;
    *(f32x4*)up = h;
    up += HDIM;
  }
}

// ---------------- fallback path (proven R1 pieces) --------------------------
__global__ __launch_bounds__(256, 2) void gemm_f32_fb(
    const float* __restrict__ X, const float* __restrict__ Bm,
    float* __restrict__ U) {
#define LDK 40
#define FBM 128
#define FBK 32
#define FNT (HDIM / FBK)
  __shared__ __align__(16) short As[2][FBM * LDK];
  __shared__ __align__(16) short Bs[2][FBM * LDK];
  const int wg  = blockIdx.x;
  const int cpx = (TDIM / FBM) * (HDIM / FBM) / 8;
  const int swz = (wg & 7) * cpx + (wg >> 3);
  const int tm = swz >> 4;
  const int tn = swz & 15;
  const int row0 = tm * FBM, col0 = tn * FBM;
  const int tid  = threadIdx.x;
  const int lane = tid & 63;
  const int wid  = tid >> 6;
  const int wr = (wid >> 1) * 64;
  const int wc = (wid & 1) * 64;
  const int srow = tid >> 2;
  const int sk   = (tid & 3) << 3;
  const float* gA  = X  + (size_t)(row0 + srow) * HDIM + sk;
  const float* gA2 = gA + 64 * HDIM;
  const float* gB  = Bm + (size_t)(col0 + srow) * HDIM + sk;
  const float* gB2 = gB + 64 * HDIM;
  f32x4 a00, a01, a10, a11, b00, b01, b10, b11;
#define LOADREG(kt) do {                                                      \
    const float* p;                                                           \
    p = gA  + (kt) * FBK; a00 = *(const f32x4*)p; a01 = *(const f32x4*)(p+4); \
    p = gA2 + (kt) * FBK; a10 = *(const f32x4*)p; a11 = *(const f32x4*)(p+4); \
    p = gB  + (kt) * FBK; b00 = *(const f32x4*)p; b01 = *(const f32x4*)(p+4); \
    p = gB2 + (kt) * FBK; b10 = *(const f32x4*)p; b11 = *(const f32x4*)(p+4); \
  } while (0)
#define CVT8(v, lo, hi) do {                                                  \
    v[0] = f2bf(lo[0]); v[1] = f2bf(lo[1]); v[2] = f2bf(lo[2]);               \
    v[3] = f2bf(lo[3]); v[4] = f2bf(hi[0]); v[5] = f2bf(hi[1]);               \
    v[6] = f2bf(hi[2]); v[7] = f2bf(hi[3]);                                   \
  } while (0)
#define DSWRITE(buf) do {                                                     \
    s16x8 v;                                                                  \
    CVT8(v, a00, a01); *(s16x8*)&As[buf][srow * LDK + sk] = v;                \
    CVT8(v, a10, a11); *(s16x8*)&As[buf][(srow + 64) * LDK + sk] = v;         \
    CVT8(v, b00, b01); *(s16x8*)&Bs[buf][srow * LDK + sk] = v;                \
    CVT8(v, b10, b11); *(s16x8*)&Bs[buf][(srow + 64) * LDK + sk] = v;         \
  } while (0)
  f32x4 acc[4][4] = {};
#define COMPUTE(buf) do {                                                     \
    const int r16_ = lane & 15;                                               \
    const int ks_  = (lane >> 4) * 8;                                         \
    s16x8 af[4], bfr[4];                                                      \
    _Pragma("unroll") for (int m = 0; m < 4; ++m)                             \
      af[m] = *(const s16x8*)&As[buf][(wr + m * 16 + r16_) * LDK + ks_];      \
    _Pragma("unroll") for (int n = 0; n < 4; ++n)                             \
      bfr[n] = *(const s16x8*)&Bs[buf][(wc + n * 16 + r16_) * LDK + ks_];     \
    _Pragma("unroll") for (int m = 0; m < 4; ++m)                             \
      _Pragma("unroll") for (int n = 0; n < 4; ++n)                           \
        acc[m][n] = __builtin_amdgcn_mfma_f32_16x16x32_bf16(                  \
            af[m], bfr[n], acc[m][n], 0, 0, 0);                               \
  } while (0)
  LOADREG(0);
  DSWRITE(0);
  __syncthreads();
#pragma unroll 2
  for (int kt = 0; kt < FNT; ++kt) {
    const int cur = kt & 1;
    if (kt + 1 < FNT) LOADREG(kt + 1);
    COMPUTE(cur);
    if (kt + 1 < FNT) DSWRITE(cur ^ 1);
    __syncthreads();
  }
  const int crow = wr + ((lane >> 4) << 2);
  const int ccol = wc + (lane & 15);
#pragma unroll
  for (int m = 0; m < 4; ++m)
#pragma unroll
    for (int n = 0; n < 4; ++n)
#pragma unroll
      for (int j = 0; j < 4; ++j)
        U[(size_t)(row0 + crow + m * 16 + j) * HDIM + (col0 + ccol + n * 16)] =
            acc[m][n][j];
#undef LOADREG
#undef CVT8
#undef DSWRITE
#undef COMPUTE
#undef LDK
#undef FBM
#undef FBK
#undef FNT
}

__global__ void scan_pass1(const float* __restrict__ U,
                           const float* __restrict__ lam,
                           float* __restrict__ e) {
  const int c = (blockIdx.y * 256 + threadIdx.x) * 4;
  const int j = blockIdx.x;
  const f32x4 l4 = *(const f32x4*)&lam[c];
  f32x4 h = {0.f, 0.f, 0.f, 0.f};
  const float* up = U + (size_t)j * LCH * HDIM + c;
#pragma unroll 4
  for (int t = 0; t < LCH; ++t) {
    f32x4 u4 = *(const f32x4*)up;
    h = l4 * h + u4;
    up += HDIM;
  }
  *(f32x4*)&e[(size_t)j * HDIM + c] = h;
}

extern "C" void kernel_launch(void* const* d_in, const int* in_sizes, int n_in,
                              void* d_out, int out_size, void* d_ws, size_t ws_size,
                              hipStream_t stream) {
  const float* X   = (const float*)d_in[0];
  const float* lam = (const float*)d_in[1];
  const float* Bm  = (const float*)d_in[2];
  float* U = (float*)d_out;              // u then h, in-place

  if (ws_size >= WS_NEED) {
    short* Bb = (short*)d_ws;
    float* e  = (float*)((char*)d_ws + BBF_BYTES);

    hipFuncSetAttribute((const void*)gemm_fused3,
                        hipFuncAttributeMaxDynamicSharedMemorySize, 131072);

    cvt_B<<<dim3(HDIM * HDIM / 4096), dim3(256), 0, stream>>>(Bm, Bb);
    gemm_fused3<<<dim3((TDIM / BM) * (HDIM / BN)), dim3(512), 131072, stream>>>(
        X, Bb, lam, U, e);
    scan_carry<<<dim3(HDIM / 1024), dim3(256), 0, stream>>>(e, lam);
    scan_pass3<<<dim3(GCH, HDIM / 1024), dim3(256), 0, stream>>>(U, lam, e);
  } else {
    float* e = (float*)d_ws;
    gemm_f32_fb<<<dim3((TDIM / 128) * (HDIM / 128)), dim3(256), 0, stream>>>(
        X, Bm, U);
    scan_pass1<<<dim3(GCH, HDIM / 1024), dim3(256), 0, stream>>>(U, lam, e);
    scan_carry<<<dim3(HDIM / 1024), dim3(256), 0, stream>>>(e, lam);
    scan_pass3<<<dim3(GCH, HDIM / 1024), dim3(256), 0, stream>>>(U, lam, e);
  }
}